// Round 5
// baseline (589.089 us; speedup 1.0000x reference)
//
#include <hip/hip_runtime.h>

#define VOCAB   100000
#define EMB     128
#define CLASSES 1000
#define BATCH   16384
#define SEQLEN  200
#define SLICES  8
#define SLICE_SZ (VOCAB / SLICES)   // 12500 rows = 3.2 MB bf16: fits one XCD L2

typedef short bf16x8 __attribute__((ext_vector_type(8)));
typedef float f32x4  __attribute__((ext_vector_type(4)));

__device__ __forceinline__ unsigned short f32_to_bf16(float f) {
    unsigned int u = __builtin_bit_cast(unsigned int, f);
    u += 0x7fffu + ((u >> 16) & 1u);   // round-to-nearest-even
    return (unsigned short)(u >> 16);
}
__device__ __forceinline__ float bf_lo(unsigned int p) { return __builtin_bit_cast(float, p << 16); }
__device__ __forceinline__ float bf_hi(unsigned int p) { return __builtin_bit_cast(float, p & 0xffff0000u); }

__device__ __forceinline__ bf16x8 pack_bf16x8(float4 u, float4 v) {
    bf16x8 r;
    r[0] = (short)f32_to_bf16(u.x); r[1] = (short)f32_to_bf16(u.y);
    r[2] = (short)f32_to_bf16(u.z); r[3] = (short)f32_to_bf16(u.w);
    r[4] = (short)f32_to_bf16(v.x); r[5] = (short)f32_to_bf16(v.y);
    r[6] = (short)f32_to_bf16(v.z); r[7] = (short)f32_to_bf16(v.w);
    return r;
}

// One dispatch: blocks [0,6250) convert emb f32->bf16 (8 elts/thread exact);
// [6250,6313) convert fc_w; [6313,7337) zero the f32 pooled accumulator.
__global__ __launch_bounds__(256) void convert_all(const float* __restrict__ emb,
                                                   const float* __restrict__ fcw,
                                                   unsigned short* __restrict__ eb,
                                                   unsigned short* __restrict__ wb,
                                                   float* __restrict__ pool) {
    if (blockIdx.x >= 6313) {                    // zero pooled: 1024 blocks x 2048 f32
        const long i = ((long)(blockIdx.x - 6313) * 256 + threadIdx.x) * 8;
        float4 z = {0.f, 0.f, 0.f, 0.f};
        *(float4*)(pool + i) = z;
        *(float4*)(pool + i + 4) = z;
        return;
    }
    const float* src;
    unsigned short* dst;
    long i;
    if (blockIdx.x < 6250) {
        i = ((long)blockIdx.x * 256 + threadIdx.x) * 8;
        src = emb; dst = eb;
    } else {
        i = (((long)blockIdx.x - 6250) * 256 + threadIdx.x) * 8;
        if (i >= (long)CLASSES * EMB) return;
        src = fcw; dst = wb;
    }
    float4 v0 = *(const float4*)(src + i);
    float4 v1 = *(const float4*)(src + i + 4);
    uint4 o;
    o.x = (unsigned int)f32_to_bf16(v0.x) | ((unsigned int)f32_to_bf16(v0.y) << 16);
    o.y = (unsigned int)f32_to_bf16(v0.z) | ((unsigned int)f32_to_bf16(v0.w) << 16);
    o.z = (unsigned int)f32_to_bf16(v1.x) | ((unsigned int)f32_to_bf16(v1.y) << 16);
    o.w = (unsigned int)f32_to_bf16(v1.z) | ((unsigned int)f32_to_bf16(v1.w) << 16);
    *(uint4*)(dst + i) = o;
}

// XCD-sliced masked embedding-bag.  Grid = (BATCH/4)*8 blocks, 4 waves/block.
// slice = blockIdx&7: with round-robin block->XCD dispatch each XCD only
// gathers its own 3.2 MB table slice -> slice stays L2-resident (goal: kill
// the ~3.45 TB/s L2-fill ceiling seen in rounds 2-4).  Wave = (bag, slice):
// ballot-compact in-slice ids to LDS, gather 4 tokens/iter (1KB/instr),
// shfl-reduce, atomicAdd the 128-dim f32 partial into pooled.
__global__ __launch_bounds__(256) void bag_pool_sliced(const int* __restrict__ seq,
                                                       const unsigned short* __restrict__ emb,
                                                       float* __restrict__ pooled) {
    __shared__ int toks[4][208];
    const int lane  = threadIdx.x & 63;
    const int wid   = threadIdx.x >> 6;
    const int slice = blockIdx.x & 7;
    const int b     = (blockIdx.x >> 3) * 4 + wid;
    const int lo    = slice * SLICE_SZ;
    const int hi    = lo + SLICE_SZ;

    const int* srow = seq + b * SEQLEN;
    int cnt = 0;
#define COMPACT(T)                                                            \
    {                                                                         \
        int t = (T);                                                          \
        bool p = (t >= lo) & (t < hi) & (t != 0);                             \
        unsigned long long m = __ballot(p);                                   \
        int pr = __builtin_amdgcn_mbcnt_lo((unsigned)m, 0);                   \
        pr = __builtin_amdgcn_mbcnt_hi((unsigned)(m >> 32), pr);              \
        if (p) toks[wid][cnt + pr] = t;                                       \
        cnt += __builtin_popcountll(m);                                       \
    }
    COMPACT(srow[lane])
    COMPACT(srow[lane + 64])
    COMPACT(srow[lane + 128])
    COMPACT((lane < 8) ? srow[lane + 192] : 0)
#undef COMPACT

    const int quad = lane >> 4;
    const int dsub = (lane & 15) * 8;
    float a0 = 0.f, a1 = 0.f, a2 = 0.f, a3 = 0.f;
    float a4 = 0.f, a5 = 0.f, a6 = 0.f, a7 = 0.f;

#pragma unroll 2
    for (int i = 0; i < cnt; i += 4) {
        const int idx = i + quad;
        if (idx < cnt) {
            const int tok = toks[wid][idx];
            uint4 v = *(const uint4*)(emb + (tok << 7) + dsub);
            a0 += bf_lo(v.x); a1 += bf_hi(v.x);
            a2 += bf_lo(v.y); a3 += bf_hi(v.y);
            a4 += bf_lo(v.z); a5 += bf_hi(v.z);
            a6 += bf_lo(v.w); a7 += bf_hi(v.w);
        }
    }

    a0 += __shfl_xor(a0, 16); a1 += __shfl_xor(a1, 16);
    a2 += __shfl_xor(a2, 16); a3 += __shfl_xor(a3, 16);
    a4 += __shfl_xor(a4, 16); a5 += __shfl_xor(a5, 16);
    a6 += __shfl_xor(a6, 16); a7 += __shfl_xor(a7, 16);
    a0 += __shfl_xor(a0, 32); a1 += __shfl_xor(a1, 32);
    a2 += __shfl_xor(a2, 32); a3 += __shfl_xor(a3, 32);
    a4 += __shfl_xor(a4, 32); a5 += __shfl_xor(a5, 32);
    a6 += __shfl_xor(a6, 32); a7 += __shfl_xor(a7, 32);

    if (lane < 16 && cnt > 0) {
        float* p = pooled + b * EMB + dsub;
        atomicAdd(p + 0, a0); atomicAdd(p + 1, a1);
        atomicAdd(p + 2, a2); atomicAdd(p + 3, a3);
        atomicAdd(p + 4, a4); atomicAdd(p + 5, a5);
        atomicAdd(p + 6, a6); atomicAdd(p + 7, a7);
    }
}

// Fallback full-gather over f32 emb, plain f32 stores (if ws too small).
__global__ __launch_bounds__(256) void bag_pool_f32(const int* __restrict__ seq,
                                                    const float* __restrict__ emb,
                                                    float* __restrict__ pooled) {
    const int lane = threadIdx.x & 63;
    const int wid  = threadIdx.x >> 6;
    const int b    = blockIdx.x * 4 + wid;
    const int* srow = seq + b * SEQLEN;
    int ids0 = srow[lane];
    int ids1 = srow[lane + 64];
    int ids2 = srow[lane + 128];
    int ids3 = (lane < 8) ? srow[lane + 192] : 0;
    const int half = lane >> 5;
    const int dsub = (lane & 31) * 4;
    float4 acc = {0.f, 0.f, 0.f, 0.f};
#define PAIR_BODY(IDS, Q)                                                   \
    {                                                                       \
        int tok = __shfl((IDS), 2 * (Q) + half);                            \
        if (tok != 0) {                                                     \
            float4 v = *(const float4*)(emb + (tok << 7) + dsub);           \
            acc.x += v.x; acc.y += v.y; acc.z += v.z; acc.w += v.w;         \
        }                                                                   \
    }
#pragma unroll 8
    for (int q = 0; q < 32; ++q) PAIR_BODY(ids0, q)
#pragma unroll 8
    for (int q = 0; q < 32; ++q) PAIR_BODY(ids1, q)
#pragma unroll 8
    for (int q = 0; q < 32; ++q) PAIR_BODY(ids2, q)
#pragma unroll
    for (int q = 0; q < 4; ++q)  PAIR_BODY(ids3, q)
#undef PAIR_BODY
    acc.x += __shfl_xor(acc.x, 32);
    acc.y += __shfl_xor(acc.y, 32);
    acc.z += __shfl_xor(acc.z, 32);
    acc.w += __shfl_xor(acc.w, 32);
    if (lane < 32) *(float4*)(pooled + b * EMB + dsub) = acc;
}

// fc_w converter for the fallback path only.
__global__ __launch_bounds__(256) void convert_w(const float* __restrict__ w,
                                                 unsigned short* __restrict__ wb) {
    const int i = (blockIdx.x * 256 + threadIdx.x) * 4;   // 125 blocks
    float4 v = *(const float4*)(w + i);
    ushort4 o;
    o.x = f32_to_bf16(v.x); o.y = f32_to_bf16(v.y);
    o.z = f32_to_bf16(v.z); o.w = f32_to_bf16(v.w);
    *(ushort4*)(wb + i) = o;
}

// out[b,c] = pooled[b,:] . fc_w[c,:] + fc_b[c]   (NT GEMM, K=128, MFMA)
// A-frag read from f32 pooled, packed to bf16 once per wave, reused across
// 21 n-tiles; W-frags software-pipelined from L1/L2.
__global__ __launch_bounds__(256) void bow_gemm(const float* __restrict__ pooled,
                                                const unsigned short* __restrict__ fcw,
                                                const float* __restrict__ fcb,
                                                float* __restrict__ out) {
    const int lane = threadIdx.x & 63;
    const int wid  = threadIdx.x >> 6;
    const int quad = lane >> 4;
    const int m0   = blockIdx.x * 64 + wid * 16;
    const int mrow = m0 + (lane & 15);
    const int koff = quad * 8;                   // A[m=lane&15][k=quad*8+j]

    const float* ar = pooled + mrow * EMB + koff;
    bf16x8 a0 = pack_bf16x8(*(const float4*)(ar +  0), *(const float4*)(ar +  4));
    bf16x8 a1 = pack_bf16x8(*(const float4*)(ar + 32), *(const float4*)(ar + 36));
    bf16x8 a2 = pack_bf16x8(*(const float4*)(ar + 64), *(const float4*)(ar + 68));
    bf16x8 a3 = pack_bf16x8(*(const float4*)(ar + 96), *(const float4*)(ar + 100));

    int ccur = (blockIdx.y * 21) * 16 + (lane & 15);   // 3 x 21 tiles cover 63
    const unsigned short* wr = fcw + ((ccur < CLASSES) ? ccur : 0) * EMB + koff;
    bf16x8 w0 = *(const bf16x8*)(wr + 0 * 32);
    bf16x8 w1 = *(const bf16x8*)(wr + 1 * 32);
    bf16x8 w2 = *(const bf16x8*)(wr + 2 * 32);
    bf16x8 w3 = *(const bf16x8*)(wr + 3 * 32);

#pragma unroll 1
    for (int i = 0; i < 21; ++i) {
        bf16x8 c0 = w0, c1 = w1, c2 = w2, c3 = w3;
        const int cc = ccur;
        if (i + 1 < 21) {
            ccur += 16;
            const unsigned short* wn = fcw + ((ccur < CLASSES) ? ccur : 0) * EMB + koff;
            w0 = *(const bf16x8*)(wn + 0 * 32);
            w1 = *(const bf16x8*)(wn + 1 * 32);
            w2 = *(const bf16x8*)(wn + 2 * 32);
            w3 = *(const bf16x8*)(wn + 3 * 32);
        }
        f32x4 acc = {0.f, 0.f, 0.f, 0.f};
        acc = __builtin_amdgcn_mfma_f32_16x16x32_bf16(a0, c0, acc, 0, 0, 0);
        acc = __builtin_amdgcn_mfma_f32_16x16x32_bf16(a1, c1, acc, 0, 0, 0);
        acc = __builtin_amdgcn_mfma_f32_16x16x32_bf16(a2, c2, acc, 0, 0, 0);
        acc = __builtin_amdgcn_mfma_f32_16x16x32_bf16(a3, c3, acc, 0, 0, 0);

        if (cc < CLASSES) {
            const float bias = fcb[cc];
            float* orow = out + (long)(m0 + quad * 4) * CLASSES + cc;
#pragma unroll
            for (int r = 0; r < 4; ++r)          // C/D: col=lane&15, row=quad*4+r
                orow[(long)r * CLASSES] = acc[r] + bias;
        }
    }
}

extern "C" void kernel_launch(void* const* d_in, const int* in_sizes, int n_in,
                              void* d_out, int out_size, void* d_ws, size_t ws_size,
                              hipStream_t stream) {
    const int*   seq = (const int*)d_in[0];
    const float* emb = (const float*)d_in[1];   // f32 [VOCAB, EMB]
    const float* fcw = (const float*)d_in[2];   // f32 [CLASSES, EMB]
    const float* fcb = (const float*)d_in[3];   // f32 [CLASSES]
    float*       out = (float*)d_out;           // f32 [BATCH, CLASSES]

    float*          pooled   = (float*)d_ws;                        // f32 [BATCH, EMB]    8 MB
    unsigned short* fcw_bf16 = (unsigned short*)(pooled + (long)BATCH * EMB);  // 250 KB
    unsigned short* emb_bf16 = fcw_bf16 + (long)CLASSES * EMB;      // bf16 [VOCAB, EMB]  25.6 MB

    const size_t need = (size_t)BATCH * EMB * 4 +
                        ((size_t)CLASSES * EMB + (size_t)VOCAB * EMB) * 2;

    if (ws_size >= need) {
        convert_all<<<7337, 256, 0, stream>>>(emb, fcw, emb_bf16, fcw_bf16, pooled);
        bag_pool_sliced<<<(BATCH / 4) * SLICES, 256, 0, stream>>>(seq, emb_bf16, pooled);
    } else {
        convert_w<<<125, 256, 0, stream>>>(fcw, fcw_bf16);
        bag_pool_f32<<<BATCH / 4, 256, 0, stream>>>(seq, emb, pooled);
    }
    bow_gemm<<<dim3(BATCH / 64, 3), 256, 0, stream>>>(pooled, fcw_bf16, fcb, out);
}

// Round 6
// 250.842 us; speedup vs baseline: 2.3484x; 2.3484x over previous
//
#include <hip/hip_runtime.h>

#define VOCAB   100000
#define EMB     128
#define CLASSES 1000
#define BATCH   16384
#define SEQLEN  200
#define SLICES  8
#define SLICE_SZ (VOCAB / SLICES)     // 12500 rows = 3.2 MB bf16: fits one XCD L2
#define PSTRIDE ((long)BATCH * EMB)   // elements per partial slice plane

typedef short bf16x8 __attribute__((ext_vector_type(8)));
typedef float f32x4  __attribute__((ext_vector_type(4)));

__device__ __forceinline__ unsigned short f32_to_bf16(float f) {
    unsigned int u = __builtin_bit_cast(unsigned int, f);
    u += 0x7fffu + ((u >> 16) & 1u);   // round-to-nearest-even
    return (unsigned short)(u >> 16);
}
__device__ __forceinline__ float bf_lo(unsigned int p) { return __builtin_bit_cast(float, p << 16); }
__device__ __forceinline__ float bf_hi(unsigned int p) { return __builtin_bit_cast(float, p & 0xffff0000u); }
__device__ __forceinline__ unsigned int pack2(float a, float b) {
    return (unsigned int)f32_to_bf16(a) | ((unsigned int)f32_to_bf16(b) << 16);
}

// blocks [0,6250): emb f32->bf16 (8 elts/thread exact); [6250,6313): fc_w.
__global__ __launch_bounds__(256) void convert_all(const float* __restrict__ emb,
                                                   const float* __restrict__ fcw,
                                                   unsigned short* __restrict__ eb,
                                                   unsigned short* __restrict__ wb) {
    const float* src;
    unsigned short* dst;
    long i;
    if (blockIdx.x < 6250) {
        i = ((long)blockIdx.x * 256 + threadIdx.x) * 8;
        src = emb; dst = eb;
    } else {
        i = (((long)blockIdx.x - 6250) * 256 + threadIdx.x) * 8;
        if (i >= (long)CLASSES * EMB) return;
        src = fcw; dst = wb;
    }
    float4 v0 = *(const float4*)(src + i);
    float4 v1 = *(const float4*)(src + i + 4);
    uint4 o;
    o.x = pack2(v0.x, v0.y);
    o.y = pack2(v0.z, v0.w);
    o.z = pack2(v1.x, v1.y);
    o.w = pack2(v1.z, v1.w);
    *(uint4*)(dst + i) = o;
}

// XCD-sliced masked embedding-bag, v2: private partials, NO atomics.
// Grid = (BATCH/4)*8; slice = blockIdx&7 rides round-robin block->XCD so each
// XCD gathers only its own 3.2 MB L2-resident slice (R5 proved FETCH 85 MB).
// Wave = (bag, slice): ballot-compact in-slice ids to LDS, gather 4 rows/iter
// (1 KB/instr), shfl-reduce, then ONE plain coalesced 256 B bf16 store into
// part[slice][bag][:].  R5's atomicAdd epilogue caused 524 MB of cross-XCD
// 32B RMWs and 448 us of latency; this replaces it with 34 MB streaming.
__global__ __launch_bounds__(256) void bag_pool_sliced(const int* __restrict__ seq,
                                                       const unsigned short* __restrict__ emb,
                                                       unsigned short* __restrict__ part) {
    __shared__ int toks[4][208];
    const int lane  = threadIdx.x & 63;
    const int wid   = threadIdx.x >> 6;
    const int slice = blockIdx.x & 7;
    const int b     = (blockIdx.x >> 3) * 4 + wid;
    const int lo    = slice * SLICE_SZ;
    const int hi    = lo + SLICE_SZ;

    const int* srow = seq + b * SEQLEN;
    int cnt = 0;
#define COMPACT(T)                                                            \
    {                                                                         \
        int t = (T);                                                          \
        bool p = (t >= lo) & (t < hi) & (t != 0);                             \
        unsigned long long m = __ballot(p);                                   \
        int pr = __builtin_amdgcn_mbcnt_lo((unsigned)m, 0);                   \
        pr = __builtin_amdgcn_mbcnt_hi((unsigned)(m >> 32), pr);              \
        if (p) toks[wid][cnt + pr] = t;                                       \
        cnt += __builtin_popcountll(m);                                       \
    }
    COMPACT(srow[lane])
    COMPACT(srow[lane + 64])
    COMPACT(srow[lane + 128])
    COMPACT((lane < 8) ? srow[lane + 192] : 0)
#undef COMPACT

    const int quad = lane >> 4;
    const int dsub = (lane & 15) * 8;
    float a0 = 0.f, a1 = 0.f, a2 = 0.f, a3 = 0.f;
    float a4 = 0.f, a5 = 0.f, a6 = 0.f, a7 = 0.f;

#pragma unroll 2
    for (int i = 0; i < cnt; i += 4) {
        const int idx = i + quad;
        if (idx < cnt) {
            const int tok = toks[wid][idx];
            uint4 v = *(const uint4*)(emb + (tok << 7) + dsub);
            a0 += bf_lo(v.x); a1 += bf_hi(v.x);
            a2 += bf_lo(v.y); a3 += bf_hi(v.y);
            a4 += bf_lo(v.z); a5 += bf_hi(v.z);
            a6 += bf_lo(v.w); a7 += bf_hi(v.w);
        }
    }

    a0 += __shfl_xor(a0, 16); a1 += __shfl_xor(a1, 16);
    a2 += __shfl_xor(a2, 16); a3 += __shfl_xor(a3, 16);
    a4 += __shfl_xor(a4, 16); a5 += __shfl_xor(a5, 16);
    a6 += __shfl_xor(a6, 16); a7 += __shfl_xor(a7, 16);
    a0 += __shfl_xor(a0, 32); a1 += __shfl_xor(a1, 32);
    a2 += __shfl_xor(a2, 32); a3 += __shfl_xor(a3, 32);
    a4 += __shfl_xor(a4, 32); a5 += __shfl_xor(a5, 32);
    a6 += __shfl_xor(a6, 32); a7 += __shfl_xor(a7, 32);

    if (lane < 16) {    // unconditional: zero partial when cnt==0 (ws is poisoned)
        uint4 o;
        o.x = pack2(a0, a1);
        o.y = pack2(a2, a3);
        o.z = pack2(a4, a5);
        o.w = pack2(a6, a7);
        *(uint4*)(part + (long)slice * PSTRIDE + (long)b * EMB + dsub) = o;
    }
}

// GEMM with folded 8-way partial reduction.  Grid (256,1): each block owns 64
// bag-rows and ALL 63 n-tiles, so partials are read exactly once (33.5 MB).
// A-prep: sum 8 bf16 partials in f32, pack to bf16 frags; W software-pipelined.
__global__ __launch_bounds__(256) void bow_gemm_red(const unsigned short* __restrict__ part,
                                                    const unsigned short* __restrict__ fcw,
                                                    const float* __restrict__ fcb,
                                                    float* __restrict__ out) {
    const int lane = threadIdx.x & 63;
    const int wid  = threadIdx.x >> 6;
    const int quad = lane >> 4;
    const int m0   = blockIdx.x * 64 + wid * 16;
    const int mrow = m0 + (lane & 15);
    const int koff = quad * 8;                   // A[m=lane&15][k=quad*8+j]

    float s[32];
#pragma unroll
    for (int j = 0; j < 32; ++j) s[j] = 0.f;
    const unsigned short* pp = part + (long)mrow * EMB + koff;
#pragma unroll
    for (int sl = 0; sl < 8; ++sl) {
        const unsigned short* q = pp + (long)sl * PSTRIDE;
#pragma unroll
        for (int f = 0; f < 4; ++f) {
            uint4 t = *(const uint4*)(q + f * 32);
            s[f*8+0] += bf_lo(t.x); s[f*8+1] += bf_hi(t.x);
            s[f*8+2] += bf_lo(t.y); s[f*8+3] += bf_hi(t.y);
            s[f*8+4] += bf_lo(t.z); s[f*8+5] += bf_hi(t.z);
            s[f*8+6] += bf_lo(t.w); s[f*8+7] += bf_hi(t.w);
        }
    }
    bf16x8 af[4];
#pragma unroll
    for (int f = 0; f < 4; ++f)
#pragma unroll
        for (int j = 0; j < 8; ++j) af[f][j] = (short)f32_to_bf16(s[f*8+j]);

    int ccur = lane & 15;                        // tile 0 column
    const unsigned short* wr = fcw + (long)ccur * EMB + koff;
    bf16x8 w0 = *(const bf16x8*)(wr + 0 * 32);
    bf16x8 w1 = *(const bf16x8*)(wr + 1 * 32);
    bf16x8 w2 = *(const bf16x8*)(wr + 2 * 32);
    bf16x8 w3 = *(const bf16x8*)(wr + 3 * 32);

#pragma unroll 1
    for (int i = 0; i < 63; ++i) {
        bf16x8 c0 = w0, c1 = w1, c2 = w2, c3 = w3;
        const int cc = ccur;
        if (i + 1 < 63) {                        // prefetch next tile's W-frag
            ccur += 16;
            const unsigned short* wn = fcw + (long)((ccur < CLASSES) ? ccur : 0) * EMB + koff;
            w0 = *(const bf16x8*)(wn + 0 * 32);
            w1 = *(const bf16x8*)(wn + 1 * 32);
            w2 = *(const bf16x8*)(wn + 2 * 32);
            w3 = *(const bf16x8*)(wn + 3 * 32);
        }
        f32x4 acc = {0.f, 0.f, 0.f, 0.f};
        acc = __builtin_amdgcn_mfma_f32_16x16x32_bf16(af[0], c0, acc, 0, 0, 0);
        acc = __builtin_amdgcn_mfma_f32_16x16x32_bf16(af[1], c1, acc, 0, 0, 0);
        acc = __builtin_amdgcn_mfma_f32_16x16x32_bf16(af[2], c2, acc, 0, 0, 0);
        acc = __builtin_amdgcn_mfma_f32_16x16x32_bf16(af[3], c3, acc, 0, 0, 0);

        if (cc < CLASSES) {
            const float bias = fcb[cc];
            float* orow = out + (long)(m0 + quad * 4) * CLASSES + cc;
#pragma unroll
            for (int r = 0; r < 4; ++r)          // C/D: col=lane&15, row=quad*4+r
                orow[(long)r * CLASSES] = acc[r] + bias;
        }
    }
}

// ---------- Fallback path (ws too small for partials): round-3/4 structure ----------
__global__ __launch_bounds__(256) void bag_pool_bf16(const int* __restrict__ seq,
                                                     const unsigned short* __restrict__ emb,
                                                     unsigned short* __restrict__ pooled) {
    const int lane = threadIdx.x & 63;
    const int wid  = threadIdx.x >> 6;
    const int b    = blockIdx.x * 4 + wid;
    const int* srow = seq + (long)b * SEQLEN;
    int ids0 = srow[lane];
    int ids1 = srow[lane + 64];
    int ids2 = srow[lane + 128];
    int ids3 = (lane < 8) ? srow[lane + 192] : 0;
    const int quad = lane >> 4;
    const int dsub = (lane & 15) * 8;
    float a0 = 0.f, a1 = 0.f, a2 = 0.f, a3 = 0.f;
    float a4 = 0.f, a5 = 0.f, a6 = 0.f, a7 = 0.f;
#define GBODY(IDS, QL)                                                        \
    {                                                                         \
        int tok = __shfl((IDS), 4 * (QL) + quad);                             \
        if (tok != 0) {                                                       \
            uint4 v = *(const uint4*)(emb + ((long)tok << 7) + dsub);         \
            a0 += bf_lo(v.x); a1 += bf_hi(v.x);                               \
            a2 += bf_lo(v.y); a3 += bf_hi(v.y);                               \
            a4 += bf_lo(v.z); a5 += bf_hi(v.z);                               \
            a6 += bf_lo(v.w); a7 += bf_hi(v.w);                               \
        }                                                                     \
    }
#pragma unroll 8
    for (int q = 0; q < 16; ++q) GBODY(ids0, q)
#pragma unroll 8
    for (int q = 0; q < 16; ++q) GBODY(ids1, q)
#pragma unroll 8
    for (int q = 0; q < 16; ++q) GBODY(ids2, q)
#pragma unroll
    for (int q = 0; q < 2; ++q)  GBODY(ids3, q)
#undef GBODY
    a0 += __shfl_xor(a0, 16); a1 += __shfl_xor(a1, 16);
    a2 += __shfl_xor(a2, 16); a3 += __shfl_xor(a3, 16);
    a4 += __shfl_xor(a4, 16); a5 += __shfl_xor(a5, 16);
    a6 += __shfl_xor(a6, 16); a7 += __shfl_xor(a7, 16);
    a0 += __shfl_xor(a0, 32); a1 += __shfl_xor(a1, 32);
    a2 += __shfl_xor(a2, 32); a3 += __shfl_xor(a3, 32);
    a4 += __shfl_xor(a4, 32); a5 += __shfl_xor(a5, 32);
    a6 += __shfl_xor(a6, 32); a7 += __shfl_xor(a7, 32);
    if (lane < 16) {
        uint4 o;
        o.x = pack2(a0, a1);
        o.y = pack2(a2, a3);
        o.z = pack2(a4, a5);
        o.w = pack2(a6, a7);
        *(uint4*)(pooled + (long)b * EMB + dsub) = o;
    }
}

__global__ __launch_bounds__(256) void bow_gemm_b(const unsigned short* __restrict__ pooled,
                                                  const unsigned short* __restrict__ fcw,
                                                  const float* __restrict__ fcb,
                                                  float* __restrict__ out) {
    const int lane = threadIdx.x & 63;
    const int wid  = threadIdx.x >> 6;
    const int quad = lane >> 4;
    const int m0   = blockIdx.x * 64 + wid * 16;
    const int mrow = m0 + (lane & 15);
    const int koff = quad * 8;

    const unsigned short* ar = pooled + (long)mrow * EMB + koff;
    bf16x8 a0 = *(const bf16x8*)(ar + 0 * 32);
    bf16x8 a1 = *(const bf16x8*)(ar + 1 * 32);
    bf16x8 a2 = *(const bf16x8*)(ar + 2 * 32);
    bf16x8 a3 = *(const bf16x8*)(ar + 3 * 32);

    int ccur = (blockIdx.y * 21) * 16 + (lane & 15);
    const unsigned short* wr = fcw + (long)((ccur < CLASSES) ? ccur : 0) * EMB + koff;
    bf16x8 w0 = *(const bf16x8*)(wr + 0 * 32);
    bf16x8 w1 = *(const bf16x8*)(wr + 1 * 32);
    bf16x8 w2 = *(const bf16x8*)(wr + 2 * 32);
    bf16x8 w3 = *(const bf16x8*)(wr + 3 * 32);

#pragma unroll 1
    for (int i = 0; i < 21; ++i) {
        bf16x8 c0 = w0, c1 = w1, c2 = w2, c3 = w3;
        const int cc = ccur;
        if (i + 1 < 21) {
            ccur += 16;
            const unsigned short* wn = fcw + (long)((ccur < CLASSES) ? ccur : 0) * EMB + koff;
            w0 = *(const bf16x8*)(wn + 0 * 32);
            w1 = *(const bf16x8*)(wn + 1 * 32);
            w2 = *(const bf16x8*)(wn + 2 * 32);
            w3 = *(const bf16x8*)(wn + 3 * 32);
        }
        f32x4 acc = {0.f, 0.f, 0.f, 0.f};
        acc = __builtin_amdgcn_mfma_f32_16x16x32_bf16(a0, c0, acc, 0, 0, 0);
        acc = __builtin_amdgcn_mfma_f32_16x16x32_bf16(a1, c1, acc, 0, 0, 0);
        acc = __builtin_amdgcn_mfma_f32_16x16x32_bf16(a2, c2, acc, 0, 0, 0);
        acc = __builtin_amdgcn_mfma_f32_16x16x32_bf16(a3, c3, acc, 0, 0, 0);
        if (cc < CLASSES) {
            const float bias = fcb[cc];
            float* orow = out + (long)(m0 + quad * 4) * CLASSES + cc;
#pragma unroll
            for (int r = 0; r < 4; ++r)
                orow[(long)r * CLASSES] = acc[r] + bias;
        }
    }
}

extern "C" void kernel_launch(void* const* d_in, const int* in_sizes, int n_in,
                              void* d_out, int out_size, void* d_ws, size_t ws_size,
                              hipStream_t stream) {
    const int*   seq = (const int*)d_in[0];
    const float* emb = (const float*)d_in[1];   // f32 [VOCAB, EMB]
    const float* fcw = (const float*)d_in[2];   // f32 [CLASSES, EMB]
    const float* fcb = (const float*)d_in[3];   // f32 [CLASSES]
    float*       out = (float*)d_out;           // f32 [BATCH, CLASSES]

    const size_t need_A = (size_t)SLICES * BATCH * EMB * 2 +
                          (size_t)CLASSES * EMB * 2 + (size_t)VOCAB * EMB * 2;   // ~59.4 MB

    if (ws_size >= need_A) {
        unsigned short* part     = (unsigned short*)d_ws;               // bf16 [8][BATCH][EMB] 33.5 MB
        unsigned short* fcw_bf16 = part + SLICES * PSTRIDE;             // 256 KB
        unsigned short* emb_bf16 = fcw_bf16 + (long)CLASSES * EMB;      // 25.6 MB
        convert_all<<<6313, 256, 0, stream>>>(emb, fcw, emb_bf16, fcw_bf16);
        bag_pool_sliced<<<(BATCH / 4) * SLICES, 256, 0, stream>>>(seq, emb_bf16, part);
        bow_gemm_red<<<BATCH / 64, 256, 0, stream>>>(part, fcw_bf16, fcb, out);
    } else {
        unsigned short* pooled   = (unsigned short*)d_ws;               // bf16 [BATCH][EMB] 4 MB
        unsigned short* fcw_bf16 = pooled + PSTRIDE;                    // 256 KB
        unsigned short* emb_bf16 = fcw_bf16 + (long)CLASSES * EMB;      // 25.6 MB
        convert_all<<<6313, 256, 0, stream>>>(emb, fcw, emb_bf16, fcw_bf16);
        bag_pool_bf16<<<BATCH / 4, 256, 0, stream>>>(seq, emb_bf16, pooled);
        bow_gemm_b<<<dim3(BATCH / 64, 3), 256, 0, stream>>>(pooled, fcw_bf16, fcb, out);
    }
}